// Round 6
// baseline (15146.288 us; speedup 1.0000x reference)
//
#include <hip/hip_runtime.h>
#include <math.h>

// ---------------------------------------------------------------------------
// SpatialTransformer forward, fp32 end-to-end.
// conv0(1x1)+BN+ReLU folded analytically (BN stats from 16x16 moment matrix),
// then 5x [conv3x3(valid)+maxpool3s2+BN+ReLU] -> LRN(128) -> GEMV(7x2048)
// -> spectral-norm scan -> affine_grid + grid_sample(reflect) * sigmoid(m).
// Conv biases cancel exactly in training-mode BN and are skipped.
// R11: R10's pipelined conv3pool, LDS-compacted to regain occupancy
// (R10: 44KB -> ~2 blocks/CU, Occupancy 23%). Changes:
//  - unpadded contiguous 4-plane chunk (4x1156 = 4624 floats) staged by 19
//    uniform DMA slices (slice 18 source-clamped, overshoot lands in the
//    buffer's own 240-float pad) -> off[19] folds plane idx, one base/chunk
//  - s_wt single-buffered (two-barrier structure already makes it safe)
//  - LDS 40448 B <= 40960 -> 4 blocks/CU at VGPR<=128.
// Pipeline unchanged: issue next chunk's 19 DMA + 2 weight loads, counted
// s_waitcnt vmcnt(21) (drains current chunk only), raw s_barrier, compute.
// ---------------------------------------------------------------------------

#define CO_PB 8     // output channels per conv3pool block
#define PLANE 1156  // 34*34, unpadded
#define CHUNK 4624  // 4*PLANE, staged contiguously
#define CHUNKP 4864 // 19*256, padded staging extent per buffer

__device__ __forceinline__ void gld_lds4(const float* g, float* l) {
  __builtin_amdgcn_global_load_lds(
      (const __attribute__((address_space(1))) void*)(g),
      (__attribute__((address_space(3))) void*)(l), 4, 0, 0);
}

// ---------------- util: zero a small region --------------------------------
__global__ void zero_kernel(float* __restrict__ p, int n) {
  int i = blockIdx.x * 256 + threadIdx.x;
  if (i < n) p[i] = 0.f;
}

// ---------------- moments of x: sums[16], upper-tri products[136] ----------
__global__ __launch_bounds__(256) void moment_kernel(
    const float* __restrict__ x, float* __restrict__ mom) {
  const int tid = threadIdx.x;
  int q = blockIdx.x * 256 + tid;  // 0..200703 quad index
  int n = q / 12544, pq = q - n * 12544;
  const float* xb = x + ((long)n * 16) * 50176 + pq * 4;
  float4 v4[16];
#pragma unroll
  for (int i = 0; i < 16; ++i) v4[i] = *(const float4*)(xb + (long)i * 50176);
  float accs[16];
  float accp[136];
#pragma unroll
  for (int i = 0; i < 16; ++i) accs[i] = 0.f;
#pragma unroll
  for (int k = 0; k < 136; ++k) accp[k] = 0.f;
#pragma unroll
  for (int p = 0; p < 4; ++p) {
    float v[16];
#pragma unroll
    for (int i = 0; i < 16; ++i)
      v[i] = (p == 0) ? v4[i].x : (p == 1) ? v4[i].y : (p == 2) ? v4[i].z : v4[i].w;
#pragma unroll
    for (int i = 0; i < 16; ++i) accs[i] += v[i];
    int k = 0;
#pragma unroll
    for (int i = 0; i < 16; ++i)
#pragma unroll
      for (int j = i; j < 16; ++j) { accp[k] += v[i] * v[j]; ++k; }
  }
  __shared__ float s_part[4][152];
  const int lane = tid & 63, wv = tid >> 6;
#pragma unroll
  for (int k = 0; k < 16; ++k) {
    float t = accs[k];
#pragma unroll
    for (int o = 32; o; o >>= 1) t += __shfl_down(t, o, 64);
    if (lane == 0) s_part[wv][k] = t;
  }
#pragma unroll
  for (int k = 0; k < 136; ++k) {
    float t = accp[k];
#pragma unroll
    for (int o = 32; o; o >>= 1) t += __shfl_down(t, o, 64);
    if (lane == 0) s_part[wv][16 + k] = t;
  }
  __syncthreads();
  if (tid < 152) {
    float t = s_part[0][tid] + s_part[1][tid] + s_part[2][tid] + s_part[3][tid];
    atomicAdd(&mom[tid], t);
  }
}

// ---------------- fold conv0 + BN into W' x + b' ---------------------------
__global__ void foldbn_kernel(const float* __restrict__ w0,
                              const float* __restrict__ mom,
                              const float* __restrict__ g,
                              const float* __restrict__ b,
                              float* __restrict__ Wp, float* __restrict__ bp) {
  int c = threadIdx.x;
  if (c >= 128) return;
  const float invN = 1.f / 802816.f;
  float w[16], m[16];
#pragma unroll
  for (int i = 0; i < 16; ++i) { w[i] = w0[c * 16 + i]; m[i] = mom[i] * invN; }
  float mu = 0.f;
#pragma unroll
  for (int i = 0; i < 16; ++i) mu += w[i] * m[i];
  float ey2 = 0.f;
  int k = 0;
#pragma unroll
  for (int i = 0; i < 16; ++i)
#pragma unroll
    for (int j = i; j < 16; ++j) {
      float Mij = mom[16 + k] * invN;
      ey2 += ((i == j) ? 1.f : 2.f) * w[i] * w[j] * Mij;
      ++k;
    }
  float var = ey2 - mu * mu;
  float al = g[c] * rsqrtf(var + 1e-5f);
#pragma unroll
  for (int i = 0; i < 16; ++i) Wp[c * 16 + i] = al * w[i];
  bp[c] = b[c] - al * mu;
}

// ---------------- stage 0 folded: act = relu(W' x + b'), 2 images ----------
__global__ __launch_bounds__(256) void conv0act_kernel(
    const float* __restrict__ x, const float* __restrict__ Wp,
    const float* __restrict__ bp, float* __restrict__ act, int n_base) {
  __shared__ float sw[512];
  __shared__ float sb[32];
  const int tid = threadIdx.x;
  const int co0 = blockIdx.y * 32;
  for (int e = tid; e < 512; e += 256) sw[e] = Wp[co0 * 16 + e];
  if (tid < 32) sb[tid] = bp[co0 + tid];
  __syncthreads();
  const int q = blockIdx.x * 256 + tid;  // 0..12543 quad within image
  const int nloc = blockIdx.z;
  const float* xb = x + ((long)(n_base + nloc) * 16) * 50176 + q * 4;
  float4 v4[16];
#pragma unroll
  for (int i = 0; i < 16; ++i) v4[i] = *(const float4*)(xb + (long)i * 50176);
  float* ob = act + ((long)nloc * 128) * 50176 + q * 4;
  for (int u = 0; u < 32; ++u) {
    float bb = sb[u];
    float4 a = make_float4(bb, bb, bb, bb);
#pragma unroll
    for (int i = 0; i < 16; ++i) {
      float w = sw[u * 16 + i];
      a.x += w * v4[i].x; a.y += w * v4[i].y;
      a.z += w * v4[i].z; a.w += w * v4[i].w;
    }
    a.x = fmaxf(a.x, 0.f); a.y = fmaxf(a.y, 0.f);
    a.z = fmaxf(a.z, 0.f); a.w = fmaxf(a.w, 0.f);
    *(float4*)(ob + (long)(co0 + u) * 50176) = a;
  }
}

// ---------------- per-channel BN statistics (sum, sumsq) -------------------
__global__ __launch_bounds__(256) void stats_kernel(
    const float* __restrict__ buf, float* __restrict__ stats, int P2) {
  const int c = blockIdx.x;
  const int n = blockIdx.y;
  const int tid = threadIdx.x;
  const float* b = buf + ((long)n * 128 + c) * P2;
  float s = 0.f, q = 0.f;
  for (int i = tid; i < P2; i += 256) {
    float v = b[i];
    s += v; q += v * v;
  }
  __shared__ float rs[256], rq[256];
  rs[tid] = s; rq[tid] = q;
  __syncthreads();
  for (int off = 128; off; off >>= 1) {
    if (tid < off) { rs[tid] += rs[tid + off]; rq[tid] += rq[tid + off]; }
    __syncthreads();
  }
  if (tid == 0) {
    atomicAdd(&stats[c], rs[0]);
    atomicAdd(&stats[128 + c], rq[0]);
  }
}

// ---------------- apply BN + ReLU in place ---------------------------------
__global__ __launch_bounds__(256) void bnrelu_kernel(
    float* __restrict__ buf, const float* __restrict__ stats,
    const float* __restrict__ g, const float* __restrict__ b,
    int P2, float invM, long total) {
  long i = (long)blockIdx.x * 256 + threadIdx.x;
  if (i >= total) return;
  int c = (int)((i / P2) & 127);
  float mu = stats[c] * invM;
  float var = stats[128 + c] * invM - mu * mu;
  float al = g[c] * rsqrtf(var + 1e-5f);
  float v = buf[i];
  buf[i] = fmaxf(al * (v - mu) + b[c], 0.f);
}

// ---------------- fused conv3x3(valid, no bias) + maxpool3s2 ---------------
// grid: x = tiles^2 (15x15 pooled tiles), y = 16 co-groups (CO_PB=8),
// z = images. One 2x2 conv patch per thread (16x16 patch grid).
// Software-pipelined K-loop: double-buffered s_in (contiguous 4-plane
// chunk, 19 uniform DMA slices), single-buffered s_wt; per chunk issue
// next chunk's 19 DMA + 2 weight loads, counted s_waitcnt vmcnt(21)
// drains only the CURRENT chunk (prefetch stays in flight across the raw
// s_barrier), then compute. Chunk-invariant offsets hoisted per block.
__global__ __launch_bounds__(256, 4) void conv3pool_kernel(
    const float* __restrict__ in, const float* __restrict__ wt,
    float* __restrict__ out, int Sin, int Pout, int n_base) {
  const int tid = threadIdx.x;
  const int tilesX = (Pout + 14) / 15;
  const int ty = blockIdx.x / tilesX, tx = blockIdx.x - ty * tilesX;
  const int co0 = blockIdx.y * CO_PB;
  const int nloc = blockIdx.z;
  const int py0 = ty * 15, px0 = tx * 15;
  const int iy0 = py0 * 2, ix0 = px0 * 2;

  __shared__ __align__(16) float s_in[2][CHUNKP];  // double-buffered chunk
  __shared__ __align__(16) float s_wt[4][CO_PB][12];  // single-buffered

  const int pi = tid >> 4, pj = tid & 15;  // this thread's 2x2 conv patch

  // ---- chunk-invariant staging source offsets (clamped), j = 0..18 ----
  // element e of the flat 4-plane chunk: plane p = e/1156, r = e%1156,
  // row = r/34, col = r%34; off[j] = p*S2 + clamp(gy)*Sin + clamp(gx).
  // Slice 18 overshoot (e >= 4624) is clamped to e=4623 (reads valid data,
  // lands in the buffer's own pad region 4624..4863).
  const long S2 = (long)Sin * Sin;
  int off[19];
#pragma unroll
  for (int j = 0; j < 19; ++j) {
    int e = tid + 256 * j;
    if (e > CHUNK - 1) e = CHUNK - 1;
    int p = e / 1156, r = e - p * 1156;
    int rr = r / 34, cc = r - 34 * rr;
    int gy = iy0 + rr; if (gy > Sin - 1) gy = Sin - 1;
    int gx = ix0 + cc; if (gx > Sin - 1) gx = Sin - 1;
    off[j] = p * (int)S2 + gy * Sin + gx;  // memory-safe; clamped values
  }                                        // only feed discarded outputs

  // ---- chunk-invariant weight staging offsets (288 elems: tid, tid+256) ---
  int wg0, wl0, wg1, wl1;
  {
    int e = tid;
    int cil = e / 72, rem = e - 72 * cil, u = rem / 9, t = rem - 9 * u;
    wg0 = ((co0 + u) * 128 + cil) * 9 + t;
    wl0 = (cil * CO_PB + u) * 12 + t;
    e = tid + 256;  // index only VALID for tid < 32 (ds_write is guarded);
    cil = e / 72; rem = e - 72 * cil; u = rem / 9; t = rem - 9 * u;
    wg1 = ((co0 + u) * 128 + cil) * 9 + t;  // global idx stays in-bounds
    wl1 = (cil * CO_PB + u) * 12 + t;
  }

  float acc[CO_PB][4];
#pragma unroll
  for (int u = 0; u < CO_PB; ++u)
#pragma unroll
    for (int k = 0; k < 4; ++k) acc[u][k] = 0.f;

  const float* inN = in + ((long)nloc * 128) * S2;  // ch 0 of this image
  const int wb = tid & 192;                         // wave-uniform LDS base

  // issue one chunk's 19 DMA slices (uniform per wave)
  auto issue_dma = [&](int c0, int b) {
    const float* src = inN + (long)c0 * S2;
    float* dp = &s_in[b][wb];
#pragma unroll
    for (int j = 0; j < 19; ++j) gld_lds4(src + off[j], dp + j * 256);
  };

  // ---- prologue: chunk 0 in flight (FIFO: [19 DMA][2 wloads]) ----
  issue_dma(0, 0);
  float w0v = wt[wg0];
  float w1v = wt[wg1];  // all lanes load (uniform vmcnt); ds_write guarded

  for (int ci0 = 0; ci0 < 128; ci0 += 4) {
    const int cur = (ci0 >> 2) & 1;
    float w0n = 0.f, w1n = 0.f;
    if (ci0 < 124) {
      issue_dma(ci0 + 4, cur ^ 1);          // +19 DMA (next chunk)
      w0n = wt[wg0 + 9 * (ci0 + 4)];        // +1
      w1n = wt[wg1 + 9 * (ci0 + 4)];        // +1
      // drain chunk ci0's [19 DMA][2 w]; keep next chunk's 21 in flight
      asm volatile("s_waitcnt vmcnt(21)" ::: "memory");
    } else {
      asm volatile("s_waitcnt vmcnt(0)" ::: "memory");
    }
    __builtin_amdgcn_sched_barrier(0);
    // current chunk's weights (drained above) -> LDS (single buffer: safe,
    // previous chunk's readers finished before the trailing barrier)
    ((float*)&s_wt[0][0][0])[wl0] = w0v;
    if (tid < 32) ((float*)&s_wt[0][0][0])[wl1] = w1v;
    asm volatile("s_waitcnt lgkmcnt(0)" ::: "memory");
    __builtin_amdgcn_sched_barrier(0);
    __builtin_amdgcn_s_barrier();  // all waves: DMA(cur)+wt(cur) visible

#pragma unroll
    for (int cil = 0; cil < 4; ++cil) {
      const float* ip = &s_in[cur][cil * PLANE] + (2 * pi) * 34 + 2 * pj;
      float iv[16];
#pragma unroll
      for (int r = 0; r < 4; ++r) {
        float2 a = *(const float2*)(ip + r * 34);
        float2 b = *(const float2*)(ip + r * 34 + 2);
        iv[r * 4 + 0] = a.x; iv[r * 4 + 1] = a.y;
        iv[r * 4 + 2] = b.x; iv[r * 4 + 3] = b.y;
      }
#pragma unroll
      for (int u = 0; u < CO_PB; ++u) {
        const float4* wq = (const float4*)&s_wt[cil][u][0];
        float4 q0 = wq[0], q1 = wq[1], q2 = wq[2];
        float wv[9] = {q0.x, q0.y, q0.z, q0.w, q1.x, q1.y, q1.z, q1.w, q2.x};
#pragma unroll
        for (int ky = 0; ky < 3; ++ky)
#pragma unroll
          for (int kx = 0; kx < 3; ++kx) {
            float w = wv[ky * 3 + kx];
            acc[u][0] += w * iv[ky * 4 + kx];
            acc[u][1] += w * iv[ky * 4 + kx + 1];
            acc[u][2] += w * iv[(ky + 1) * 4 + kx];
            acc[u][3] += w * iv[(ky + 1) * 4 + kx + 1];
          }
      }
    }
    // all waves done READING s_in[cur] and s_wt before next iter overwrites
    __builtin_amdgcn_s_barrier();
    w0v = w0n; w1v = w1n;
  }

  // pooling via LDS staging of the 32x32 conv tile (stride 33), per co.
  // FULLY UNROLLED so acc[] indices stay compile-time constants.
  float* s_conv = &s_in[0][0];
  const int gpy = py0 + pi, gpx = px0 + pj;
  const bool wvalid = (pi < 15) && (pj < 15) && (gpy < Pout) && (gpx < Pout);
  float* cp = s_conv + (2 * pi) * 33 + 2 * pj;
  const float* rp = s_conv + (2 * pi) * 33 + 2 * pj;  // pool read base
#pragma unroll
  for (int u = 0; u < CO_PB; ++u) {
    __syncthreads();
    cp[0] = acc[u][0]; cp[1] = acc[u][1];
    cp[33] = acc[u][2]; cp[34] = acc[u][3];
    __syncthreads();
    if (wvalid) {
      float mx = rp[0];
#pragma unroll
      for (int dy = 0; dy < 3; ++dy)
#pragma unroll
        for (int dx = 0; dx < 3; ++dx)
          mx = fmaxf(mx, rp[dy * 33 + dx]);
      out[(((long)(n_base + nloc) * 128 + (co0 + u)) * Pout + gpy) * Pout + gpx] = mx;
    }
  }
}

// ---------------- LRN, size = 128 over the channel axis --------------------
__global__ __launch_bounds__(128) void lrn_kernel(float* __restrict__ buf) {
  const int n = blockIdx.x;
  const int c = threadIdx.x;
  __shared__ float sq[128];
  float* b = buf + (long)n * 2048;
  for (int p = 0; p < 16; ++p) {
    float v = b[c * 16 + p];
    sq[c] = v * v;
    __syncthreads();
    int lo = c - 64 < 0 ? 0 : c - 64;
    int hi = c + 63 > 127 ? 127 : c + 63;
    float win = 0.f;
    for (int j = lo; j <= hi; ++j) win += sq[j];
    b[c * 16 + p] = v * powf(1.f + (1e-4f / 128.f) * win, -0.75f);
    __syncthreads();
  }
}

// ---------------- regression head: reg = xs @ Wr.T + br --------------------
__global__ __launch_bounds__(256) void gemv_kernel(
    const float* __restrict__ xs, const float* __restrict__ Wr,
    const float* __restrict__ br, float* __restrict__ reg) {
  const int n = blockIdx.x;
  const int tid = threadIdx.x;
  float a[7] = {0.f, 0.f, 0.f, 0.f, 0.f, 0.f, 0.f};
  for (int e = tid; e < 2048; e += 256) {
    float v = xs[(long)n * 2048 + e];
#pragma unroll
    for (int j = 0; j < 7; ++j) a[j] += v * Wr[j * 2048 + e];
  }
  __shared__ float red[256];
  for (int j = 0; j < 7; ++j) {
    red[tid] = a[j];
    __syncthreads();
    for (int off = 128; off; off >>= 1) {
      if (tid < off) red[tid] += red[tid + off];
      __syncthreads();
    }
    if (tid == 0) reg[n * 7 + j] = red[0] + br[j];
    __syncthreads();
  }
}

// ---------------- spectral norm (sequential scan over batch) ---------------
__global__ void sn_kernel(const float* __restrict__ reg,
                          const float* __restrict__ u0g,
                          const float* __restrict__ v0g,
                          float* __restrict__ theta, float* __restrict__ m) {
  if (threadIdx.x != 0 || blockIdx.x != 0) return;
  float u[2] = {u0g[0], u0g[1]};
  float v[3] = {v0g[0], v0g[1], v0g[2]};
  for (int n = 0; n < 16; ++n) {
    const float* W = reg + n * 7;
    for (int it = 0; it < 4; ++it) {
      float v0n = W[0] * u[0] + W[3] * u[1];
      float v1n = W[1] * u[0] + W[4] * u[1];
      float v2n = W[2] * u[0] + W[5] * u[1];
      float nv = sqrtf(v0n * v0n + v1n * v1n + v2n * v2n);
      nv = fmaxf(nv, 1e-12f);
      v[0] = v0n / nv; v[1] = v1n / nv; v[2] = v2n / nv;
      float u0n = W[0] * v[0] + W[1] * v[1] + W[2] * v[2];
      float u1n = W[3] * v[0] + W[4] * v[1] + W[5] * v[2];
      float nu = sqrtf(u0n * u0n + u1n * u1n);
      nu = fmaxf(nu, 1e-12f);
      u[0] = u0n / nu; u[1] = u1n / nu;
    }
    float Wv0 = W[0] * v[0] + W[1] * v[1] + W[2] * v[2];
    float Wv1 = W[3] * v[0] + W[4] * v[1] + W[5] * v[2];
    float sigma = u[0] * Wv0 + u[1] * Wv1;
    for (int k = 0; k < 6; ++k) theta[n * 6 + k] = W[k] / sigma;
    m[n] = 1.f / (1.f + expf(-W[6]));
  }
}

// ---------------- affine grid + reflect grid_sample + mask scale -----------
__device__ __forceinline__ float reflectf(float x, float size) {
  x = fabsf(x + 0.5f);
  x = fmodf(x, 2.f * size);
  if (x > size) x = 2.f * size - x;
  x -= 0.5f;
  return fminf(fmaxf(x, 0.f), size - 1.f);
}

__global__ __launch_bounds__(256) void sample_kernel(
    const float* __restrict__ x, const float* __restrict__ theta,
    const float* __restrict__ m, float* __restrict__ out) {
  long i = (long)blockIdx.x * 256 + threadIdx.x;
  if (i >= 12845056L) return;
  int w = (int)(i % 224);
  long t = i / 224;
  int h = (int)(t % 224); t /= 224;
  int c = (int)(t % 16);
  int n = (int)(t / 16);
  const float* th = theta + n * 6;
  float xn = (2 * w + 1) * (1.f / 224.f) - 1.f;
  float yn = (2 * h + 1) * (1.f / 224.f) - 1.f;
  float gx = th[0] * xn + th[1] * yn + th[2];
  float gy = th[3] * xn + th[4] * yn + th[5];
  float ix = reflectf(((gx + 1.f) * 224.f - 1.f) * 0.5f, 224.f);
  float iy = reflectf(((gy + 1.f) * 224.f - 1.f) * 0.5f, 224.f);
  float x0 = floorf(ix), y0 = floorf(iy);
  float wx = ix - x0, wy = iy - y0;
  int x0i = (int)x0; if (x0i < 0) x0i = 0; if (x0i > 223) x0i = 223;
  int y0i = (int)y0; if (y0i < 0) y0i = 0; if (y0i > 223) y0i = 223;
  int x1i = (int)x0 + 1; if (x1i < 0) x1i = 0; if (x1i > 223) x1i = 223;
  int y1i = (int)y0 + 1; if (y1i < 0) y1i = 0; if (y1i > 223) y1i = 223;
  const float* im = x + ((long)n * 16 + c) * 50176;
  float v00 = im[y0i * 224 + x0i], v01 = im[y0i * 224 + x1i];
  float v10 = im[y1i * 224 + x0i], v11 = im[y1i * 224 + x1i];
  float val = v00 * (1.f - wx) * (1.f - wy) + v01 * wx * (1.f - wy) +
              v10 * (1.f - wx) * wy + v11 * wx * wy;
  out[i] = val * m[n];
}

// ---------------------------------------------------------------------------
extern "C" void kernel_launch(void* const* d_in, const int* in_sizes, int n_in,
                              void* d_out, int out_size, void* d_ws,
                              size_t ws_size, hipStream_t stream) {
  const float* x       = (const float*)d_in[0];
  const float* conv0_w = (const float*)d_in[1];
  // d_in[2] conv0_b: cancels in BN, unused
  const float* convs_w = (const float*)d_in[3];
  // d_in[4] convs_b: cancels in BN, unused
  const float* bn_g = (const float*)d_in[5];
  const float* bn_b = (const float*)d_in[6];
  const float* Wr   = (const float*)d_in[7];
  const float* br   = (const float*)d_in[8];
  const float* u0   = (const float*)d_in[9];
  const float* v0   = (const float*)d_in[10];
  float* out = (float*)d_out;
  float* ws  = (float*)d_ws;

  // ws layout (floats): total 24,783,616 (~94.6 MiB)
  float* bufB   = ws;                  // 24,780,800 (16,128,110,110)
  float* stats  = ws + 24780800L;      // 256
  float* mom    = stats + 256;         // 152 (pad 160)
  float* Wp     = mom + 160;           // 2048
  float* bp     = Wp + 2048;           // 128
  float* regb   = bp + 128;            // 112
  float* thetab = regb + 112;          // 96
  float* mb     = thetab + 96;         // 16

  // d_out scratch: tempAct = 2 images x (128,224,224) = 12,845,056 floats
  // (exactly out_size); bufC (<=5,750,272 floats) reuses d_out after stage 1.
  float* tempAct = out;
  float* bufC    = out;

  // ---- stage-0 BN stats analytically from x moments; fold into W', b' ----
  zero_kernel<<<2, 256, 0, stream>>>(stats, 416);  // stats + mom
  moment_kernel<<<784, 256, 0, stream>>>(x, mom);
  foldbn_kernel<<<1, 128, 0, stream>>>(conv0_w, mom, bn_g, bn_b, Wp, bp);

  // ---- stage 0+1 in 8 rounds of 2 images ----
  for (int r = 0; r < 8; ++r) {
    conv0act_kernel<<<dim3(49, 4, 2), 256, 0, stream>>>(x, Wp, bp, tempAct,
                                                        2 * r);
    conv3pool_kernel<<<dim3(64, 16, 2), 256, 0, stream>>>(
        tempAct, convs_w, bufB, 224, 110, 2 * r);
  }
  zero_kernel<<<1, 256, 0, stream>>>(stats, 256);
  stats_kernel<<<dim3(128, 16), 256, 0, stream>>>(bufB, stats, 12100);
  {
    long total = 16L * 128 * 12100;
    bnrelu_kernel<<<(int)((total + 255) / 256), 256, 0, stream>>>(
        bufB, stats, bn_g + 128, bn_b + 128, 12100, 1.f / (16.f * 12100.f),
        total);
  }

  // ---- stages 2..5: ping-pong bufB <-> bufC(d_out) ----
  const int Sins[4]  = {110, 53, 25, 11};
  const int Pouts[4] = {53, 25, 11, 4};
  for (int s = 0; s < 4; ++s) {
    float* ib = (s % 2 == 0) ? bufB : bufC;
    float* ob = (s % 2 == 0) ? bufC : bufB;
    int Sin = Sins[s], Pout = Pouts[s];
    int tiles = (Pout + 14) / 15;
    conv3pool_kernel<<<dim3(tiles * tiles, 16, 16), 256, 0, stream>>>(
        ib, convs_w + (long)(s + 1) * 128 * 128 * 9, ob, Sin, Pout, 0);
    zero_kernel<<<1, 256, 0, stream>>>(stats, 256);
    int P2 = Pout * Pout;
    stats_kernel<<<dim3(128, 16), 256, 0, stream>>>(ob, stats, P2);
    long total = 16L * 128 * P2;
    bnrelu_kernel<<<(int)((total + 255) / 256), 256, 0, stream>>>(
        ob, stats, bn_g + (s + 2) * 128, bn_b + (s + 2) * 128, P2,
        1.f / (16.f * P2), total);
  }

  // ---- tail: LRN -> GEMV -> spectral norm -> sample (overwrites d_out) ----
  lrn_kernel<<<16, 128, 0, stream>>>(bufB);
  gemv_kernel<<<16, 256, 0, stream>>>(bufB, Wr, br, regb);
  sn_kernel<<<1, 1, 0, stream>>>(regb, u0, v0, thetab, mb);
  sample_kernel<<<50176, 256, 0, stream>>>(x, thetab, mb, out);
}

// Round 7
// 15109.216 us; speedup vs baseline: 1.0025x; 1.0025x over previous
//
#include <hip/hip_runtime.h>
#include <math.h>

// ---------------------------------------------------------------------------
// SpatialTransformer forward, fp32 end-to-end.
// conv0(1x1)+BN+ReLU folded analytically (BN stats from 16x16 moment matrix),
// then 5x [conv3x3(valid)+maxpool3s2+BN+ReLU] -> LRN(128) -> GEMV(7x2048)
// -> spectral-norm scan -> affine_grid + grid_sample(reflect) * sigmoid(m).
// Conv biases cancel exactly in training-mode BN and are skipped.
// R12: fixes R11's scratch-spill regression (off[19] was runtime-indexed ->
// demoted to scratch -> 5.5GB FETCH / 5.7GB WRITE of spill traffic, VGPR=64).
// Same 40448B LDS (4 blocks/CU) but R10's register footprint: planes padded
// to 1216; per chunk 16 full DMA slices (4 planes x 4, shared off[4] +
// per-plane base) + 3 tail slices covering the 4x192 plane tails (192=3x64
// so tails are wave-aligned: wave-uniform dest tb[3], per-thread src
// offT[3]). 10 hoisted ints total. DMA uniform 19+2/wave -> vmcnt(21).
// Pipeline unchanged from R10: issue next chunk, counted drain of current,
// raw s_barrier, compute; s_wt single-buffered.
// ---------------------------------------------------------------------------

#define CO_PB 8     // output channels per conv3pool block
#define PLANE 1216  // 34*34=1156 padded to 19*64 (tail pad 1156..1215)
#define CHUNKP 4864 // 4*PLANE per buffer

__device__ __forceinline__ void gld_lds4(const float* g, float* l) {
  __builtin_amdgcn_global_load_lds(
      (const __attribute__((address_space(1))) void*)(g),
      (__attribute__((address_space(3))) void*)(l), 4, 0, 0);
}

// ---------------- util: zero a small region --------------------------------
__global__ void zero_kernel(float* __restrict__ p, int n) {
  int i = blockIdx.x * 256 + threadIdx.x;
  if (i < n) p[i] = 0.f;
}

// ---------------- moments of x: sums[16], upper-tri products[136] ----------
__global__ __launch_bounds__(256) void moment_kernel(
    const float* __restrict__ x, float* __restrict__ mom) {
  const int tid = threadIdx.x;
  int q = blockIdx.x * 256 + tid;  // 0..200703 quad index
  int n = q / 12544, pq = q - n * 12544;
  const float* xb = x + ((long)n * 16) * 50176 + pq * 4;
  float4 v4[16];
#pragma unroll
  for (int i = 0; i < 16; ++i) v4[i] = *(const float4*)(xb + (long)i * 50176);
  float accs[16];
  float accp[136];
#pragma unroll
  for (int i = 0; i < 16; ++i) accs[i] = 0.f;
#pragma unroll
  for (int k = 0; k < 136; ++k) accp[k] = 0.f;
#pragma unroll
  for (int p = 0; p < 4; ++p) {
    float v[16];
#pragma unroll
    for (int i = 0; i < 16; ++i)
      v[i] = (p == 0) ? v4[i].x : (p == 1) ? v4[i].y : (p == 2) ? v4[i].z : v4[i].w;
#pragma unroll
    for (int i = 0; i < 16; ++i) accs[i] += v[i];
    int k = 0;
#pragma unroll
    for (int i = 0; i < 16; ++i)
#pragma unroll
      for (int j = i; j < 16; ++j) { accp[k] += v[i] * v[j]; ++k; }
  }
  __shared__ float s_part[4][152];
  const int lane = tid & 63, wv = tid >> 6;
#pragma unroll
  for (int k = 0; k < 16; ++k) {
    float t = accs[k];
#pragma unroll
    for (int o = 32; o; o >>= 1) t += __shfl_down(t, o, 64);
    if (lane == 0) s_part[wv][k] = t;
  }
#pragma unroll
  for (int k = 0; k < 136; ++k) {
    float t = accp[k];
#pragma unroll
    for (int o = 32; o; o >>= 1) t += __shfl_down(t, o, 64);
    if (lane == 0) s_part[wv][16 + k] = t;
  }
  __syncthreads();
  if (tid < 152) {
    float t = s_part[0][tid] + s_part[1][tid] + s_part[2][tid] + s_part[3][tid];
    atomicAdd(&mom[tid], t);
  }
}

// ---------------- fold conv0 + BN into W' x + b' ---------------------------
__global__ void foldbn_kernel(const float* __restrict__ w0,
                              const float* __restrict__ mom,
                              const float* __restrict__ g,
                              const float* __restrict__ b,
                              float* __restrict__ Wp, float* __restrict__ bp) {
  int c = threadIdx.x;
  if (c >= 128) return;
  const float invN = 1.f / 802816.f;
  float w[16], m[16];
#pragma unroll
  for (int i = 0; i < 16; ++i) { w[i] = w0[c * 16 + i]; m[i] = mom[i] * invN; }
  float mu = 0.f;
#pragma unroll
  for (int i = 0; i < 16; ++i) mu += w[i] * m[i];
  float ey2 = 0.f;
  int k = 0;
#pragma unroll
  for (int i = 0; i < 16; ++i)
#pragma unroll
    for (int j = i; j < 16; ++j) {
      float Mij = mom[16 + k] * invN;
      ey2 += ((i == j) ? 1.f : 2.f) * w[i] * w[j] * Mij;
      ++k;
    }
  float var = ey2 - mu * mu;
  float al = g[c] * rsqrtf(var + 1e-5f);
#pragma unroll
  for (int i = 0; i < 16; ++i) Wp[c * 16 + i] = al * w[i];
  bp[c] = b[c] - al * mu;
}

// ---------------- stage 0 folded: act = relu(W' x + b'), 2 images ----------
__global__ __launch_bounds__(256) void conv0act_kernel(
    const float* __restrict__ x, const float* __restrict__ Wp,
    const float* __restrict__ bp, float* __restrict__ act, int n_base) {
  __shared__ float sw[512];
  __shared__ float sb[32];
  const int tid = threadIdx.x;
  const int co0 = blockIdx.y * 32;
  for (int e = tid; e < 512; e += 256) sw[e] = Wp[co0 * 16 + e];
  if (tid < 32) sb[tid] = bp[co0 + tid];
  __syncthreads();
  const int q = blockIdx.x * 256 + tid;  // 0..12543 quad within image
  const int nloc = blockIdx.z;
  const float* xb = x + ((long)(n_base + nloc) * 16) * 50176 + q * 4;
  float4 v4[16];
#pragma unroll
  for (int i = 0; i < 16; ++i) v4[i] = *(const float4*)(xb + (long)i * 50176);
  float* ob = act + ((long)nloc * 128) * 50176 + q * 4;
  for (int u = 0; u < 32; ++u) {
    float bb = sb[u];
    float4 a = make_float4(bb, bb, bb, bb);
#pragma unroll
    for (int i = 0; i < 16; ++i) {
      float w = sw[u * 16 + i];
      a.x += w * v4[i].x; a.y += w * v4[i].y;
      a.z += w * v4[i].z; a.w += w * v4[i].w;
    }
    a.x = fmaxf(a.x, 0.f); a.y = fmaxf(a.y, 0.f);
    a.z = fmaxf(a.z, 0.f); a.w = fmaxf(a.w, 0.f);
    *(float4*)(ob + (long)(co0 + u) * 50176) = a;
  }
}

// ---------------- per-channel BN statistics (sum, sumsq) -------------------
__global__ __launch_bounds__(256) void stats_kernel(
    const float* __restrict__ buf, float* __restrict__ stats, int P2) {
  const int c = blockIdx.x;
  const int n = blockIdx.y;
  const int tid = threadIdx.x;
  const float* b = buf + ((long)n * 128 + c) * P2;
  float s = 0.f, q = 0.f;
  for (int i = tid; i < P2; i += 256) {
    float v = b[i];
    s += v; q += v * v;
  }
  __shared__ float rs[256], rq[256];
  rs[tid] = s; rq[tid] = q;
  __syncthreads();
  for (int off = 128; off; off >>= 1) {
    if (tid < off) { rs[tid] += rs[tid + off]; rq[tid] += rq[tid + off]; }
    __syncthreads();
  }
  if (tid == 0) {
    atomicAdd(&stats[c], rs[0]);
    atomicAdd(&stats[128 + c], rq[0]);
  }
}

// ---------------- apply BN + ReLU in place ---------------------------------
__global__ __launch_bounds__(256) void bnrelu_kernel(
    float* __restrict__ buf, const float* __restrict__ stats,
    const float* __restrict__ g, const float* __restrict__ b,
    int P2, float invM, long total) {
  long i = (long)blockIdx.x * 256 + threadIdx.x;
  if (i >= total) return;
  int c = (int)((i / P2) & 127);
  float mu = stats[c] * invM;
  float var = stats[128 + c] * invM - mu * mu;
  float al = g[c] * rsqrtf(var + 1e-5f);
  float v = buf[i];
  buf[i] = fmaxf(al * (v - mu) + b[c], 0.f);
}

// ---------------- fused conv3x3(valid, no bias) + maxpool3s2 ---------------
// grid: x = tiles^2 (15x15 pooled tiles), y = 16 co-groups (CO_PB=8),
// z = images. One 2x2 conv patch per thread (16x16 patch grid).
// Software-pipelined K-loop: double-buffered s_in ([4][1216] planes),
// single-buffered s_wt; per chunk issue next chunk's 19 DMA (16 full
// slices + 3 wave-aligned tail slices) + 2 weight loads, counted
// s_waitcnt vmcnt(21) drains only the CURRENT chunk (prefetch stays in
// flight across the raw s_barrier), then compute.
__global__ __launch_bounds__(256, 4) void conv3pool_kernel(
    const float* __restrict__ in, const float* __restrict__ wt,
    float* __restrict__ out, int Sin, int Pout, int n_base) {
  const int tid = threadIdx.x;
  const int tilesX = (Pout + 14) / 15;
  const int ty = blockIdx.x / tilesX, tx = blockIdx.x - ty * tilesX;
  const int co0 = blockIdx.y * CO_PB;
  const int nloc = blockIdx.z;
  const int py0 = ty * 15, px0 = tx * 15;
  const int iy0 = py0 * 2, ix0 = px0 * 2;

  __shared__ __align__(16) float s_in[2][CHUNKP];     // double-buffered
  __shared__ __align__(16) float s_wt[4][CO_PB][12];  // single-buffered

  const int pi = tid >> 4, pj = tid & 15;  // this thread's 2x2 conv patch
  const long S2 = (long)Sin * Sin;

  // ---- chunk-invariant full-slice source offsets (clamped), j = 0..3 ----
  // element e = tid + 256j of a plane (e < 1024 < 1156, no e-clamp needed)
  int off[4];
#pragma unroll
  for (int j = 0; j < 4; ++j) {
    int e = tid + 256 * j;
    int r = e / 34, cc = e - 34 * r;
    int gy = iy0 + r; if (gy > Sin - 1) gy = Sin - 1;
    int gx = ix0 + cc; if (gx > Sin - 1) gx = Sin - 1;
    off[j] = gy * Sin + gx;            // memory-safe; clamped values only
  }                                    // feed discarded outputs

  // ---- tail slices k = 0..2: 768 elems = 4 planes x 192 tail (1024..1215)
  // 192 = 3*64 -> each wave lies in ONE plane's tail: wave-uniform dest.
  int offT[3], tb[3];
  {
    const int wv6 = tid & 192;  // wave id * 64 (wave-uniform)
#pragma unroll
    for (int k = 0; k < 3; ++k) {
      int t = tid + 256 * k;
      int p = t / 192, o = t - 192 * p;     // plane, tail element
      int e = 1024 + o;
      if (e > 1155) e = 1155;               // source clamp; dest in plane pad
      int r = e / 34, cc = e - 34 * r;
      int gy = iy0 + r; if (gy > Sin - 1) gy = Sin - 1;
      int gx = ix0 + cc; if (gx > Sin - 1) gx = Sin - 1;
      offT[k] = p * (int)S2 + gy * Sin + gx;
      int T = wv6 + 256 * k;                // lane-0 tail index (wave-uniform)
      int P = T / 192;
      tb[k] = P * PLANE + 1024 + (T - 192 * P);  // wave-uniform dest base
    }
  }

  // ---- chunk-invariant weight staging offsets (288 elems: tid, tid+256) ---
  int wg0, wl0, wg1, wl1;
  {
    int e = tid;
    int cil = e / 72, rem = e - 72 * cil, u = rem / 9, t = rem - 9 * u;
    wg0 = ((co0 + u) * 128 + cil) * 9 + t;
    wl0 = (cil * CO_PB + u) * 12 + t;
    e = tid + 256;  // index only VALID for tid < 32 (ds_write is guarded);
    cil = e / 72; rem = e - 72 * cil; u = rem / 9; t = rem - 9 * u;
    wg1 = ((co0 + u) * 128 + cil) * 9 + t;  // global idx stays in-bounds
    wl1 = (cil * CO_PB + u) * 12 + t;
  }

  float acc[CO_PB][4];
#pragma unroll
  for (int u = 0; u < CO_PB; ++u)
#pragma unroll
    for (int k = 0; k < 4; ++k) acc[u][k] = 0.f;

  const float* inN = in + ((long)nloc * 128) * S2;  // ch 0 of this image
  const int wb = tid & 192;                         // wave-uniform LDS base

  // issue one chunk's 19 DMA slices (uniform per wave: 16 full + 3 tail)
  auto issue_dma = [&](int c0, int b) {
#pragma unroll
    for (int cil = 0; cil < 4; ++cil) {
      const float* src = inN + (long)(c0 + cil) * S2;
      float* dp = &s_in[b][cil * PLANE + wb];
#pragma unroll
      for (int j = 0; j < 4; ++j) gld_lds4(src + off[j], dp + j * 256);
    }
    const float* srcT = inN + (long)c0 * S2;
#pragma unroll
    for (int k = 0; k < 3; ++k) gld_lds4(srcT + offT[k], &s_in[b][tb[k]]);
  };

  // ---- prologue: chunk 0 in flight (FIFO: [19 DMA][2 wloads]) ----
  issue_dma(0, 0);
  float w0v = wt[wg0];
  float w1v = wt[wg1];  // all lanes load (uniform vmcnt); ds_write guarded

  for (int ci0 = 0; ci0 < 128; ci0 += 4) {
    const int cur = (ci0 >> 2) & 1;
    float w0n = 0.f, w1n = 0.f;
    if (ci0 < 124) {
      issue_dma(ci0 + 4, cur ^ 1);          // +19 DMA (next chunk)
      w0n = wt[wg0 + 9 * (ci0 + 4)];        // +1
      w1n = wt[wg1 + 9 * (ci0 + 4)];        // +1
      // drain chunk ci0's [19 DMA][2 w]; keep next chunk's 21 in flight
      asm volatile("s_waitcnt vmcnt(21)" ::: "memory");
    } else {
      asm volatile("s_waitcnt vmcnt(0)" ::: "memory");
    }
    __builtin_amdgcn_sched_barrier(0);
    // current chunk's weights (drained above) -> LDS (single buffer: safe,
    // previous chunk's readers finished before the trailing barrier)
    ((float*)&s_wt[0][0][0])[wl0] = w0v;
    if (tid < 32) ((float*)&s_wt[0][0][0])[wl1] = w1v;
    asm volatile("s_waitcnt lgkmcnt(0)" ::: "memory");
    __builtin_amdgcn_sched_barrier(0);
    __builtin_amdgcn_s_barrier();  // all waves: DMA(cur)+wt(cur) visible

#pragma unroll
    for (int cil = 0; cil < 4; ++cil) {
      const float* ip = &s_in[cur][cil * PLANE] + (2 * pi) * 34 + 2 * pj;
      float iv[16];
#pragma unroll
      for (int r = 0; r < 4; ++r) {
        float2 a = *(const float2*)(ip + r * 34);
        float2 b = *(const float2*)(ip + r * 34 + 2);
        iv[r * 4 + 0] = a.x; iv[r * 4 + 1] = a.y;
        iv[r * 4 + 2] = b.x; iv[r * 4 + 3] = b.y;
      }
#pragma unroll
      for (int u = 0; u < CO_PB; ++u) {
        const float4* wq = (const float4*)&s_wt[cil][u][0];
        float4 q0 = wq[0], q1 = wq[1], q2 = wq[2];
        float wv[9] = {q0.x, q0.y, q0.z, q0.w, q1.x, q1.y, q1.z, q1.w, q2.x};
#pragma unroll
        for (int ky = 0; ky < 3; ++ky)
#pragma unroll
          for (int kx = 0; kx < 3; ++kx) {
            float w = wv[ky * 3 + kx];
            acc[u][0] += w * iv[ky * 4 + kx];
            acc[u][1] += w * iv[ky * 4 + kx + 1];
            acc[u][2] += w * iv[(ky + 1) * 4 + kx];
            acc[u][3] += w * iv[(ky + 1) * 4 + kx + 1];
          }
      }
    }
    // all waves done READING s_in[cur] and s_wt before next iter overwrites
    __builtin_amdgcn_s_barrier();
    w0v = w0n; w1v = w1n;
  }

  // pooling via LDS staging of the 32x32 conv tile (stride 33), per co.
  // FULLY UNROLLED so acc[] indices stay compile-time constants.
  float* s_conv = &s_in[0][0];
  const int gpy = py0 + pi, gpx = px0 + pj;
  const bool wvalid = (pi < 15) && (pj < 15) && (gpy < Pout) && (gpx < Pout);
  float* cp = s_conv + (2 * pi) * 33 + 2 * pj;
  const float* rp = s_conv + (2 * pi) * 33 + 2 * pj;  // pool read base
#pragma unroll
  for (int u = 0; u < CO_PB; ++u) {
    __syncthreads();
    cp[0] = acc[u][0]; cp[1] = acc[u][1];
    cp[33] = acc[u][2]; cp[34] = acc[u][3];
    __syncthreads();
    if (wvalid) {
      float mx = rp[0];
#pragma unroll
      for (int dy = 0; dy < 3; ++dy)
#pragma unroll
        for (int dx = 0; dx < 3; ++dx)
          mx = fmaxf(mx, rp[dy * 33 + dx]);
      out[(((long)(n_base + nloc) * 128 + (co0 + u)) * Pout + gpy) * Pout + gpx] = mx;
    }
  }
}

// ---------------- LRN, size = 128 over the channel axis --------------------
__global__ __launch_bounds__(128) void lrn_kernel(float* __restrict__ buf) {
  const int n = blockIdx.x;
  const int c = threadIdx.x;
  __shared__ float sq[128];
  float* b = buf + (long)n * 2048;
  for (int p = 0; p < 16; ++p) {
    float v = b[c * 16 + p];
    sq[c] = v * v;
    __syncthreads();
    int lo = c - 64 < 0 ? 0 : c - 64;
    int hi = c + 63 > 127 ? 127 : c + 63;
    float win = 0.f;
    for (int j = lo; j <= hi; ++j) win += sq[j];
    b[c * 16 + p] = v * powf(1.f + (1e-4f / 128.f) * win, -0.75f);
    __syncthreads();
  }
}

// ---------------- regression head: reg = xs @ Wr.T + br --------------------
__global__ __launch_bounds__(256) void gemv_kernel(
    const float* __restrict__ xs, const float* __restrict__ Wr,
    const float* __restrict__ br, float* __restrict__ reg) {
  const int n = blockIdx.x;
  const int tid = threadIdx.x;
  float a[7] = {0.f, 0.f, 0.f, 0.f, 0.f, 0.f, 0.f};
  for (int e = tid; e < 2048; e += 256) {
    float v = xs[(long)n * 2048 + e];
#pragma unroll
    for (int j = 0; j < 7; ++j) a[j] += v * Wr[j * 2048 + e];
  }
  __shared__ float red[256];
  for (int j = 0; j < 7; ++j) {
    red[tid] = a[j];
    __syncthreads();
    for (int off = 128; off; off >>= 1) {
      if (tid < off) red[tid] += red[tid + off];
      __syncthreads();
    }
    if (tid == 0) reg[n * 7 + j] = red[0] + br[j];
    __syncthreads();
  }
}

// ---------------- spectral norm (sequential scan over batch) ---------------
__global__ void sn_kernel(const float* __restrict__ reg,
                          const float* __restrict__ u0g,
                          const float* __restrict__ v0g,
                          float* __restrict__ theta, float* __restrict__ m) {
  if (threadIdx.x != 0 || blockIdx.x != 0) return;
  float u[2] = {u0g[0], u0g[1]};
  float v[3] = {v0g[0], v0g[1], v0g[2]};
  for (int n = 0; n < 16; ++n) {
    const float* W = reg + n * 7;
    for (int it = 0; it < 4; ++it) {
      float v0n = W[0] * u[0] + W[3] * u[1];
      float v1n = W[1] * u[0] + W[4] * u[1];
      float v2n = W[2] * u[0] + W[5] * u[1];
      float nv = sqrtf(v0n * v0n + v1n * v1n + v2n * v2n);
      nv = fmaxf(nv, 1e-12f);
      v[0] = v0n / nv; v[1] = v1n / nv; v[2] = v2n / nv;
      float u0n = W[0] * v[0] + W[1] * v[1] + W[2] * v[2];
      float u1n = W[3] * v[0] + W[4] * v[1] + W[5] * v[2];
      float nu = sqrtf(u0n * u0n + u1n * u1n);
      nu = fmaxf(nu, 1e-12f);
      u[0] = u0n / nu; u[1] = u1n / nu;
    }
    float Wv0 = W[0] * v[0] + W[1] * v[1] + W[2] * v[2];
    float Wv1 = W[3] * v[0] + W[4] * v[1] + W[5] * v[2];
    float sigma = u[0] * Wv0 + u[1] * Wv1;
    for (int k = 0; k < 6; ++k) theta[n * 6 + k] = W[k] / sigma;
    m[n] = 1.f / (1.f + expf(-W[6]));
  }
}

// ---------------- affine grid + reflect grid_sample + mask scale -----------
__device__ __forceinline__ float reflectf(float x, float size) {
  x = fabsf(x + 0.5f);
  x = fmodf(x, 2.f * size);
  if (x > size) x = 2.f * size - x;
  x -= 0.5f;
  return fminf(fmaxf(x, 0.f), size - 1.f);
}

__global__ __launch_bounds__(256) void sample_kernel(
    const float* __restrict__ x, const float* __restrict__ theta,
    const float* __restrict__ m, float* __restrict__ out) {
  long i = (long)blockIdx.x * 256 + threadIdx.x;
  if (i >= 12845056L) return;
  int w = (int)(i % 224);
  long t = i / 224;
  int h = (int)(t % 224); t /= 224;
  int c = (int)(t % 16);
  int n = (int)(t / 16);
  const float* th = theta + n * 6;
  float xn = (2 * w + 1) * (1.f / 224.f) - 1.f;
  float yn = (2 * h + 1) * (1.f / 224.f) - 1.f;
  float gx = th[0] * xn + th[1] * yn + th[2];
  float gy = th[3] * xn + th[4] * yn + th[5];
  float ix = reflectf(((gx + 1.f) * 224.f - 1.f) * 0.5f, 224.f);
  float iy = reflectf(((gy + 1.f) * 224.f - 1.f) * 0.5f, 224.f);
  float x0 = floorf(ix), y0 = floorf(iy);
  float wx = ix - x0, wy = iy - y0;
  int x0i = (int)x0; if (x0i < 0) x0i = 0; if (x0i > 223) x0i = 223;
  int y0i = (int)y0; if (y0i < 0) y0i = 0; if (y0i > 223) y0i = 223;
  int x1i = (int)x0 + 1; if (x1i < 0) x1i = 0; if (x1i > 223) x1i = 223;
  int y1i = (int)y0 + 1; if (y1i < 0) y1i = 0; if (y1i > 223) y1i = 223;
  const float* im = x + ((long)n * 16 + c) * 50176;
  float v00 = im[y0i * 224 + x0i], v01 = im[y0i * 224 + x1i];
  float v10 = im[y1i * 224 + x0i], v11 = im[y1i * 224 + x1i];
  float val = v00 * (1.f - wx) * (1.f - wy) + v01 * wx * (1.f - wy) +
              v10 * (1.f - wx) * wy + v11 * wx * wy;
  out[i] = val * m[n];
}

// ---------------------------------------------------------------------------
extern "C" void kernel_launch(void* const* d_in, const int* in_sizes, int n_in,
                              void* d_out, int out_size, void* d_ws,
                              size_t ws_size, hipStream_t stream) {
  const float* x       = (const float*)d_in[0];
  const float* conv0_w = (const float*)d_in[1];
  // d_in[2] conv0_b: cancels in BN, unused
  const float* convs_w = (const float*)d_in[3];
  // d_in[4] convs_b: cancels in BN, unused
  const float* bn_g = (const float*)d_in[5];
  const float* bn_b = (const float*)d_in[6];
  const float* Wr   = (const float*)d_in[7];
  const float* br   = (const float*)d_in[8];
  const float* u0   = (const float*)d_in[9];
  const float* v0   = (const float*)d_in[10];
  float* out = (float*)d_out;
  float* ws  = (float*)d_ws;

  // ws layout (floats): total 24,783,616 (~94.6 MiB)
  float* bufB   = ws;                  // 24,780,800 (16,128,110,110)
  float* stats  = ws + 24780800L;      // 256
  float* mom    = stats + 256;         // 152 (pad 160)
  float* Wp     = mom + 160;           // 2048
  float* bp     = Wp + 2048;           // 128
  float* regb   = bp + 128;            // 112
  float* thetab = regb + 112;          // 96
  float* mb     = thetab + 96;         // 16

  // d_out scratch: tempAct = 2 images x (128,224,224) = 12,845,056 floats
  // (exactly out_size); bufC (<=5,750,272 floats) reuses d_out after stage 1.
  float* tempAct = out;
  float* bufC    = out;

  // ---- stage-0 BN stats analytically from x moments; fold into W', b' ----
  zero_kernel<<<2, 256, 0, stream>>>(stats, 416);  // stats + mom
  moment_kernel<<<784, 256, 0, stream>>>(x, mom);
  foldbn_kernel<<<1, 128, 0, stream>>>(conv0_w, mom, bn_g, bn_b, Wp, bp);

  // ---- stage 0+1 in 8 rounds of 2 images ----
  for (int r = 0; r < 8; ++r) {
    conv0act_kernel<<<dim3(49, 4, 2), 256, 0, stream>>>(x, Wp, bp, tempAct,
                                                        2 * r);
    conv3pool_kernel<<<dim3(64, 16, 2), 256, 0, stream>>>(
        tempAct, convs_w, bufB, 224, 110, 2 * r);
  }
  zero_kernel<<<1, 256, 0, stream>>>(stats, 256);
  stats_kernel<<<dim3(128, 16), 256, 0, stream>>>(bufB, stats, 12100);
  {
    long total = 16L * 128 * 12100;
    bnrelu_kernel<<<(int)((total + 255) / 256), 256, 0, stream>>>(
        bufB, stats, bn_g + 128, bn_b + 128, 12100, 1.f / (16.f * 12100.f),
        total);
  }

  // ---- stages 2..5: ping-pong bufB <-> bufC(d_out) ----
  const int Sins[4]  = {110, 53, 25, 11};
  const int Pouts[4] = {53, 25, 11, 4};
  for (int s = 0; s < 4; ++s) {
    float* ib = (s % 2 == 0) ? bufB : bufC;
    float* ob = (s % 2 == 0) ? bufC : bufB;
    int Sin = Sins[s], Pout = Pouts[s];
    int tiles = (Pout + 14) / 15;
    conv3pool_kernel<<<dim3(tiles * tiles, 16, 16), 256, 0, stream>>>(
        ib, convs_w + (long)(s + 1) * 128 * 128 * 9, ob, Sin, Pout, 0);
    zero_kernel<<<1, 256, 0, stream>>>(stats, 256);
    int P2 = Pout * Pout;
    stats_kernel<<<dim3(128, 16), 256, 0, stream>>>(ob, stats, P2);
    long total = 16L * 128 * P2;
    bnrelu_kernel<<<(int)((total + 255) / 256), 256, 0, stream>>>(
        ob, stats, bn_g + (s + 2) * 128, bn_b + (s + 2) * 128, P2,
        1.f / (16.f * P2), total);
  }

  // ---- tail: LRN -> GEMV -> spectral norm -> sample (overwrites d_out) ----
  lrn_kernel<<<16, 128, 0, stream>>>(bufB);
  gemv_kernel<<<16, 256, 0, stream>>>(bufB, Wr, br, regb);
  sn_kernel<<<1, 1, 0, stream>>>(regb, u0, v0, thetab, mb);
  sample_kernel<<<50176, 256, 0, stream>>>(x, thetab, mb, out);
}

// Round 9
// 6233.432 us; speedup vs baseline: 2.4298x; 2.4239x over previous
//
#include <hip/hip_runtime.h>
#include <math.h>

// ---------------------------------------------------------------------------
// SpatialTransformer forward, fp32 end-to-end.
// conv0(1x1)+BN+ReLU folded analytically (BN stats from 16x16 moment matrix),
// then 5x [conv3x3(valid)+maxpool3s2+BN+ReLU] -> LRN(128) -> GEMV(7x2048)
// -> spectral-norm scan -> affine_grid + grid_sample(reflect) * sigmoid(m).
// Conv biases cancel exactly in training-mode BN and are skipped.
// R14 == R13 resubmitted (round 8 died on container acquisition, not the
// kernel). R13 = R10 base (proven 6680us) + SCALAR WEIGHTS. The s_wt LDS
// path cost 96 ds_read_b128 per thread per chunk (3x the input reads) for
// block-uniform values. Weights are now read directly in the FMA loop with
// an all-uniform index -> compiler emits s_load via the scalar cache into
// SGPRs (v_fmac takes the SGPR operand). Deletes: wt global loads in the
// DMA FIFO (vmcnt 22->20), ds_writes + lgkmcnt fence, 96 LDS reads/chunk,
// 3KB LDS -> s_in alone = 40960 B = exactly 4 blocks/CU (R10 had 3).
// Pipeline/staging/compute order otherwise byte-identical to R10.
// ---------------------------------------------------------------------------

#define CO_PB 8     // output channels per conv3pool block
#define PLANE 1280  // 34*34=1156 rounded to 5*256 so all 4 waves issue 5 DMAs

__device__ __forceinline__ void gld_lds4(const float* g, float* l) {
  __builtin_amdgcn_global_load_lds(
      (const __attribute__((address_space(1))) void*)(g),
      (__attribute__((address_space(3))) void*)(l), 4, 0, 0);
}

// ---------------- util: zero a small region --------------------------------
__global__ void zero_kernel(float* __restrict__ p, int n) {
  int i = blockIdx.x * 256 + threadIdx.x;
  if (i < n) p[i] = 0.f;
}

// ---------------- moments of x: sums[16], upper-tri products[136] ----------
__global__ __launch_bounds__(256) void moment_kernel(
    const float* __restrict__ x, float* __restrict__ mom) {
  const int tid = threadIdx.x;
  int q = blockIdx.x * 256 + tid;  // 0..200703 quad index
  int n = q / 12544, pq = q - n * 12544;
  const float* xb = x + ((long)n * 16) * 50176 + pq * 4;
  float4 v4[16];
#pragma unroll
  for (int i = 0; i < 16; ++i) v4[i] = *(const float4*)(xb + (long)i * 50176);
  float accs[16];
  float accp[136];
#pragma unroll
  for (int i = 0; i < 16; ++i) accs[i] = 0.f;
#pragma unroll
  for (int k = 0; k < 136; ++k) accp[k] = 0.f;
#pragma unroll
  for (int p = 0; p < 4; ++p) {
    float v[16];
#pragma unroll
    for (int i = 0; i < 16; ++i)
      v[i] = (p == 0) ? v4[i].x : (p == 1) ? v4[i].y : (p == 2) ? v4[i].z : v4[i].w;
#pragma unroll
    for (int i = 0; i < 16; ++i) accs[i] += v[i];
    int k = 0;
#pragma unroll
    for (int i = 0; i < 16; ++i)
#pragma unroll
      for (int j = i; j < 16; ++j) { accp[k] += v[i] * v[j]; ++k; }
  }
  __shared__ float s_part[4][152];
  const int lane = tid & 63, wv = tid >> 6;
#pragma unroll
  for (int k = 0; k < 16; ++k) {
    float t = accs[k];
#pragma unroll
    for (int o = 32; o; o >>= 1) t += __shfl_down(t, o, 64);
    if (lane == 0) s_part[wv][k] = t;
  }
#pragma unroll
  for (int k = 0; k < 136; ++k) {
    float t = accp[k];
#pragma unroll
    for (int o = 32; o; o >>= 1) t += __shfl_down(t, o, 64);
    if (lane == 0) s_part[wv][16 + k] = t;
  }
  __syncthreads();
  if (tid < 152) {
    float t = s_part[0][tid] + s_part[1][tid] + s_part[2][tid] + s_part[3][tid];
    atomicAdd(&mom[tid], t);
  }
}

// ---------------- fold conv0 + BN into W' x + b' ---------------------------
__global__ void foldbn_kernel(const float* __restrict__ w0,
                              const float* __restrict__ mom,
                              const float* __restrict__ g,
                              const float* __restrict__ b,
                              float* __restrict__ Wp, float* __restrict__ bp) {
  int c = threadIdx.x;
  if (c >= 128) return;
  const float invN = 1.f / 802816.f;
  float w[16], m[16];
#pragma unroll
  for (int i = 0; i < 16; ++i) { w[i] = w0[c * 16 + i]; m[i] = mom[i] * invN; }
  float mu = 0.f;
#pragma unroll
  for (int i = 0; i < 16; ++i) mu += w[i] * m[i];
  float ey2 = 0.f;
  int k = 0;
#pragma unroll
  for (int i = 0; i < 16; ++i)
#pragma unroll
    for (int j = i; j < 16; ++j) {
      float Mij = mom[16 + k] * invN;
      ey2 += ((i == j) ? 1.f : 2.f) * w[i] * w[j] * Mij;
      ++k;
    }
  float var = ey2 - mu * mu;
  float al = g[c] * rsqrtf(var + 1e-5f);
#pragma unroll
  for (int i = 0; i < 16; ++i) Wp[c * 16 + i] = al * w[i];
  bp[c] = b[c] - al * mu;
}

// ---------------- stage 0 folded: act = relu(W' x + b'), 2 images ----------
__global__ __launch_bounds__(256) void conv0act_kernel(
    const float* __restrict__ x, const float* __restrict__ Wp,
    const float* __restrict__ bp, float* __restrict__ act, int n_base) {
  __shared__ float sw[512];
  __shared__ float sb[32];
  const int tid = threadIdx.x;
  const int co0 = blockIdx.y * 32;
  for (int e = tid; e < 512; e += 256) sw[e] = Wp[co0 * 16 + e];
  if (tid < 32) sb[tid] = bp[co0 + tid];
  __syncthreads();
  const int q = blockIdx.x * 256 + tid;  // 0..12543 quad within image
  const int nloc = blockIdx.z;
  const float* xb = x + ((long)(n_base + nloc) * 16) * 50176 + q * 4;
  float4 v4[16];
#pragma unroll
  for (int i = 0; i < 16; ++i) v4[i] = *(const float4*)(xb + (long)i * 50176);
  float* ob = act + ((long)nloc * 128) * 50176 + q * 4;
  for (int u = 0; u < 32; ++u) {
    float bb = sb[u];
    float4 a = make_float4(bb, bb, bb, bb);
#pragma unroll
    for (int i = 0; i < 16; ++i) {
      float w = sw[u * 16 + i];
      a.x += w * v4[i].x; a.y += w * v4[i].y;
      a.z += w * v4[i].z; a.w += w * v4[i].w;
    }
    a.x = fmaxf(a.x, 0.f); a.y = fmaxf(a.y, 0.f);
    a.z = fmaxf(a.z, 0.f); a.w = fmaxf(a.w, 0.f);
    *(float4*)(ob + (long)(co0 + u) * 50176) = a;
  }
}

// ---------------- per-channel BN statistics (sum, sumsq) -------------------
__global__ __launch_bounds__(256) void stats_kernel(
    const float* __restrict__ buf, float* __restrict__ stats, int P2) {
  const int c = blockIdx.x;
  const int n = blockIdx.y;
  const int tid = threadIdx.x;
  const float* b = buf + ((long)n * 128 + c) * P2;
  float s = 0.f, q = 0.f;
  for (int i = tid; i < P2; i += 256) {
    float v = b[i];
    s += v; q += v * v;
  }
  __shared__ float rs[256], rq[256];
  rs[tid] = s; rq[tid] = q;
  __syncthreads();
  for (int off = 128; off; off >>= 1) {
    if (tid < off) { rs[tid] += rs[tid + off]; rq[tid] += rq[tid + off]; }
    __syncthreads();
  }
  if (tid == 0) {
    atomicAdd(&stats[c], rs[0]);
    atomicAdd(&stats[128 + c], rq[0]);
  }
}

// ---------------- apply BN + ReLU in place ---------------------------------
__global__ __launch_bounds__(256) void bnrelu_kernel(
    float* __restrict__ buf, const float* __restrict__ stats,
    const float* __restrict__ g, const float* __restrict__ b,
    int P2, float invM, long total) {
  long i = (long)blockIdx.x * 256 + threadIdx.x;
  if (i >= total) return;
  int c = (int)((i / P2) & 127);
  float mu = stats[c] * invM;
  float var = stats[128 + c] * invM - mu * mu;
  float al = g[c] * rsqrtf(var + 1e-5f);
  float v = buf[i];
  buf[i] = fmaxf(al * (v - mu) + b[c], 0.f);
}

// ---------------- fused conv3x3(valid, no bias) + maxpool3s2 ---------------
// grid: x = tiles^2 (15x15 pooled tiles), y = 16 co-groups (CO_PB=8),
// z = images. One 2x2 conv patch per thread (16x16 patch grid).
// Software-pipelined K-loop (2-phase): double-buffered s_in; per chunk
// issue next chunk's 20 global_load_lds (uniform per wave), counted
// s_waitcnt vmcnt(20) drains only the CURRENT chunk (prefetch stays in
// flight across the raw s_barrier), then compute. Weights are read
// directly in the FMA loop via an all-uniform index -> scalar loads into
// SGPRs (no LDS staging, no per-thread weight reads).
__global__ __launch_bounds__(256, 4) void conv3pool_kernel(
    const float* __restrict__ in, const float* __restrict__ wt,
    float* __restrict__ out, int Sin, int Pout, int n_base) {
  const int tid = threadIdx.x;
  const int tilesX = (Pout + 14) / 15;
  const int ty = blockIdx.x / tilesX, tx = blockIdx.x - ty * tilesX;
  const int co0 = blockIdx.y * CO_PB;
  const int nloc = blockIdx.z;
  const int py0 = ty * 15, px0 = tx * 15;
  const int iy0 = py0 * 2, ix0 = px0 * 2;

  __shared__ __align__(16) float s_in[2][4 * PLANE];  // 40960 B total

  const int pi = tid >> 4, pj = tid & 15;  // this thread's 2x2 conv patch

  // ---- chunk-invariant staging source offsets (clamped), j = 0..4 ----
  int off[5];
#pragma unroll
  for (int j = 0; j < 5; ++j) {
    int e2 = tid + 256 * j;            // element within a plane (0..1279)
    int r = e2 / 34, cc = e2 - 34 * r; // tile row / col
    int gy = iy0 + r; if (gy > Sin - 1) gy = Sin - 1;
    int gx = ix0 + cc; if (gx > Sin - 1) gx = Sin - 1;
    off[j] = gy * Sin + gx;            // clamped => memory-safe; clamped
  }                                    // values only feed discarded outputs

  float acc[CO_PB][4];
#pragma unroll
  for (int u = 0; u < CO_PB; ++u)
#pragma unroll
    for (int k = 0; k < 4; ++k) acc[u][k] = 0.f;

  const long S2 = (long)Sin * Sin;
  const float* inN = in + ((long)nloc * 128) * S2;  // ch 0 of this image
  const int wb = tid & 192;                         // wave-uniform LDS base

  // issue one chunk's 20 DMA ops (4 planes x 5 slices, uniform per wave)
  auto issue_dma = [&](int c0, int b) {
#pragma unroll
    for (int cil = 0; cil < 4; ++cil) {
      const float* src = inN + (long)(c0 + cil) * S2;
      float* dp = &s_in[b][cil * PLANE + wb];
#pragma unroll
      for (int j = 0; j < 5; ++j) gld_lds4(src + off[j], dp + j * 256);
    }
  };

  // ---- prologue: chunk 0 in flight ----
  issue_dma(0, 0);

  for (int ci0 = 0; ci0 < 128; ci0 += 4) {
    const int cur = (ci0 >> 2) & 1;
    if (ci0 < 124) {
      issue_dma(ci0 + 4, cur ^ 1);          // +20 DMA (next chunk)
      // drain chunk ci0's 20 DMA; keep next chunk's 20 in flight
      asm volatile("s_waitcnt vmcnt(20)" ::: "memory");
    } else {
      asm volatile("s_waitcnt vmcnt(0)" ::: "memory");
    }
    __builtin_amdgcn_sched_barrier(0);
    __builtin_amdgcn_s_barrier();  // all waves: DMA(cur) visible

#pragma unroll
    for (int cil = 0; cil < 4; ++cil) {
      const float* ip = &s_in[cur][cil * PLANE] + (2 * pi) * 34 + 2 * pj;
      float iv[16];
#pragma unroll
      for (int r = 0; r < 4; ++r) {
        float2 a = *(const float2*)(ip + r * 34);
        float2 b = *(const float2*)(ip + r * 34 + 2);
        iv[r * 4 + 0] = a.x; iv[r * 4 + 1] = a.y;
        iv[r * 4 + 2] = b.x; iv[r * 4 + 3] = b.y;
      }
#pragma unroll
      for (int u = 0; u < CO_PB; ++u) {
        // all-uniform index (blockIdx + loop constants) -> scalar loads
        const float* wp = wt + ((long)(co0 + u) * 128 + (ci0 + cil)) * 9;
        float wv[9];
#pragma unroll
        for (int k = 0; k < 9; ++k) wv[k] = wp[k];
#pragma unroll
        for (int ky = 0; ky < 3; ++ky)
#pragma unroll
          for (int kx = 0; kx < 3; ++kx) {
            float w = wv[ky * 3 + kx];
            acc[u][0] += w * iv[ky * 4 + kx];
            acc[u][1] += w * iv[ky * 4 + kx + 1];
            acc[u][2] += w * iv[(ky + 1) * 4 + kx];
            acc[u][3] += w * iv[(ky + 1) * 4 + kx + 1];
          }
      }
    }
    // all waves done READING s_in[cur] before next iter's DMA overwrites it
    __builtin_amdgcn_s_barrier();
  }

  // pooling via LDS staging of the 32x32 conv tile (stride 33), per co.
  // FULLY UNROLLED so acc[] indices stay compile-time constants.
  float* s_conv = &s_in[0][0];
  const int gpy = py0 + pi, gpx = px0 + pj;
  const bool wvalid = (pi < 15) && (pj < 15) && (gpy < Pout) && (gpx < Pout);
  float* cp = s_conv + (2 * pi) * 33 + 2 * pj;
  const float* rp = s_conv + (2 * pi) * 33 + 2 * pj;  // pool read base
#pragma unroll
  for (int u = 0; u < CO_PB; ++u) {
    __syncthreads();
    cp[0] = acc[u][0]; cp[1] = acc[u][1];
    cp[33] = acc[u][2]; cp[34] = acc[u][3];
    __syncthreads();
    if (wvalid) {
      float mx = rp[0];
#pragma unroll
      for (int dy = 0; dy < 3; ++dy)
#pragma unroll
        for (int dx = 0; dx < 3; ++dx)
          mx = fmaxf(mx, rp[dy * 33 + dx]);
      out[(((long)(n_base + nloc) * 128 + (co0 + u)) * Pout + gpy) * Pout + gpx] = mx;
    }
  }
}

// ---------------- LRN, size = 128 over the channel axis --------------------
__global__ __launch_bounds__(128) void lrn_kernel(float* __restrict__ buf) {
  const int n = blockIdx.x;
  const int c = threadIdx.x;
  __shared__ float sq[128];
  float* b = buf + (long)n * 2048;
  for (int p = 0; p < 16; ++p) {
    float v = b[c * 16 + p];
    sq[c] = v * v;
    __syncthreads();
    int lo = c - 64 < 0 ? 0 : c - 64;
    int hi = c + 63 > 127 ? 127 : c + 63;
    float win = 0.f;
    for (int j = lo; j <= hi; ++j) win += sq[j];
    b[c * 16 + p] = v * powf(1.f + (1e-4f / 128.f) * win, -0.75f);
    __syncthreads();
  }
}

// ---------------- regression head: reg = xs @ Wr.T + br --------------------
__global__ __launch_bounds__(256) void gemv_kernel(
    const float* __restrict__ xs, const float* __restrict__ Wr,
    const float* __restrict__ br, float* __restrict__ reg) {
  const int n = blockIdx.x;
  const int tid = threadIdx.x;
  float a[7] = {0.f, 0.f, 0.f, 0.f, 0.f, 0.f, 0.f};
  for (int e = tid; e < 2048; e += 256) {
    float v = xs[(long)n * 2048 + e];
#pragma unroll
    for (int j = 0; j < 7; ++j) a[j] += v * Wr[j * 2048 + e];
  }
  __shared__ float red[256];
  for (int j = 0; j < 7; ++j) {
    red[tid] = a[j];
    __syncthreads();
    for (int off = 128; off; off >>= 1) {
      if (tid < off) red[tid] += red[tid + off];
      __syncthreads();
    }
    if (tid == 0) reg[n * 7 + j] = red[0] + br[j];
    __syncthreads();
  }
}

// ---------------- spectral norm (sequential scan over batch) ---------------
__global__ void sn_kernel(const float* __restrict__ reg,
                          const float* __restrict__ u0g,
                          const float* __restrict__ v0g,
                          float* __restrict__ theta, float* __restrict__ m) {
  if (threadIdx.x != 0 || blockIdx.x != 0) return;
  float u[2] = {u0g[0], u0g[1]};
  float v[3] = {v0g[0], v0g[1], v0g[2]};
  for (int n = 0; n < 16; ++n) {
    const float* W = reg + n * 7;
    for (int it = 0; it < 4; ++it) {
      float v0n = W[0] * u[0] + W[3] * u[1];
      float v1n = W[1] * u[0] + W[4] * u[1];
      float v2n = W[2] * u[0] + W[5] * u[1];
      float nv = sqrtf(v0n * v0n + v1n * v1n + v2n * v2n);
      nv = fmaxf(nv, 1e-12f);
      v[0] = v0n / nv; v[1] = v1n / nv; v[2] = v2n / nv;
      float u0n = W[0] * v[0] + W[1] * v[1] + W[2] * v[2];
      float u1n = W[3] * v[0] + W[4] * v[1] + W[5] * v[2];
      float nu = sqrtf(u0n * u0n + u1n * u1n);
      nu = fmaxf(nu, 1e-12f);
      u[0] = u0n / nu; u[1] = u1n / nu;
    }
    float Wv0 = W[0] * v[0] + W[1] * v[1] + W[2] * v[2];
    float Wv1 = W[3] * v[0] + W[4] * v[1] + W[5] * v[2];
    float sigma = u[0] * Wv0 + u[1] * Wv1;
    for (int k = 0; k < 6; ++k) theta[n * 6 + k] = W[k] / sigma;
    m[n] = 1.f / (1.f + expf(-W[6]));
  }
}

// ---------------- affine grid + reflect grid_sample + mask scale -----------
__device__ __forceinline__ float reflectf(float x, float size) {
  x = fabsf(x + 0.5f);
  x = fmodf(x, 2.f * size);
  if (x > size) x = 2.f * size - x;
  x -= 0.5f;
  return fminf(fmaxf(x, 0.f), size - 1.f);
}

__global__ __launch_bounds__(256) void sample_kernel(
    const float* __restrict__ x, const float* __restrict__ theta,
    const float* __restrict__ m, float* __restrict__ out) {
  long i = (long)blockIdx.x * 256 + threadIdx.x;
  if (i >= 12845056L) return;
  int w = (int)(i % 224);
  long t = i / 224;
  int h = (int)(t % 224); t /= 224;
  int c = (int)(t % 16);
  int n = (int)(t / 16);
  const float* th = theta + n * 6;
  float xn = (2 * w + 1) * (1.f / 224.f) - 1.f;
  float yn = (2 * h + 1) * (1.f / 224.f) - 1.f;
  float gx = th[0] * xn + th[1] * yn + th[2];
  float gy = th[3] * xn + th[4] * yn + th[5];
  float ix = reflectf(((gx + 1.f) * 224.f - 1.f) * 0.5f, 224.f);
  float iy = reflectf(((gy + 1.f) * 224.f - 1.f) * 0.5f, 224.f);
  float x0 = floorf(ix), y0 = floorf(iy);
  float wx = ix - x0, wy = iy - y0;
  int x0i = (int)x0; if (x0i < 0) x0i = 0; if (x0i > 223) x0i = 223;
  int y0i = (int)y0; if (y0i < 0) y0i = 0; if (y0i > 223) y0i = 223;
  int x1i = (int)x0 + 1; if (x1i < 0) x1i = 0; if (x1i > 223) x1i = 223;
  int y1i = (int)y0 + 1; if (y1i < 0) y1i = 0; if (y1i > 223) y1i = 223;
  const float* im = x + ((long)n * 16 + c) * 50176;
  float v00 = im[y0i * 224 + x0i], v01 = im[y0i * 224 + x1i];
  float v10 = im[y1i * 224 + x0i], v11 = im[y1i * 224 + x1i];
  float val = v00 * (1.f - wx) * (1.f - wy) + v01 * wx * (1.f - wy) +
              v10 * (1.f - wx) * wy + v11 * wx * wy;
  out[i] = val * m[n];
}

// ---------------------------------------------------------------------------
extern "C" void kernel_launch(void* const* d_in, const int* in_sizes, int n_in,
                              void* d_out, int out_size, void* d_ws,
                              size_t ws_size, hipStream_t stream) {
  const float* x       = (const float*)d_in[0];
  const float* conv0_w = (const float*)d_in[1];
  // d_in[2] conv0_b: cancels in BN, unused
  const float* convs_w = (const float*)d_in[3];
  // d_in[4] convs_b: cancels in BN, unused
  const float* bn_g = (const float*)d_in[5];
  const float* bn_b = (const float*)d_in[6];
  const float* Wr   = (const float*)d_in[7];
  const float* br   = (const float*)d_in[8];
  const float* u0   = (const float*)d_in[9];
  const float* v0   = (const float*)d_in[10];
  float* out = (float*)d_out;
  float* ws  = (float*)d_ws;

  // ws layout (floats): total 24,783,616 (~94.6 MiB)
  float* bufB   = ws;                  // 24,780,800 (16,128,110,110)
  float* stats  = ws + 24780800L;      // 256
  float* mom    = stats + 256;         // 152 (pad 160)
  float* Wp     = mom + 160;           // 2048
  float* bp     = Wp + 2048;           // 128
  float* regb   = bp + 128;            // 112
  float* thetab = regb + 112;          // 96
  float* mb     = thetab + 96;         // 16

  // d_out scratch: tempAct = 2 images x (128,224,224) = 12,845,056 floats
  // (exactly out_size); bufC (<=5,750,272 floats) reuses d_out after stage 1.
  float* tempAct = out;
  float* bufC    = out;

  // ---- stage-0 BN stats analytically from x moments; fold into W', b' ----
  zero_kernel<<<2, 256, 0, stream>>>(stats, 416);  // stats + mom
  moment_kernel<<<784, 256, 0, stream>>>(x, mom);
  foldbn_kernel<<<1, 128, 0, stream>>>(conv0_w, mom, bn_g, bn_b, Wp, bp);

  // ---- stage 0+1 in 8 rounds of 2 images ----
  for (int r = 0; r < 8; ++r) {
    conv0act_kernel<<<dim3(49, 4, 2), 256, 0, stream>>>(x, Wp, bp, tempAct,
                                                        2 * r);
    conv3pool_kernel<<<dim3(64, 16, 2), 256, 0, stream>>>(
        tempAct, convs_w, bufB, 224, 110, 2 * r);
  }
  zero_kernel<<<1, 256, 0, stream>>>(stats, 256);
  stats_kernel<<<dim3(128, 16), 256, 0, stream>>>(bufB, stats, 12100);
  {
    long total = 16L * 128 * 12100;
    bnrelu_kernel<<<(int)((total + 255) / 256), 256, 0, stream>>>(
        bufB, stats, bn_g + 128, bn_b + 128, 12100, 1.f / (16.f * 12100.f),
        total);
  }

  // ---- stages 2..5: ping-pong bufB <-> bufC(d_out) ----
  const int Sins[4]  = {110, 53, 25, 11};
  const int Pouts[4] = {53, 25, 11, 4};
  for (int s = 0; s < 4; ++s) {
    float* ib = (s % 2 == 0) ? bufB : bufC;
    float* ob = (s % 2 == 0) ? bufC : bufB;
    int Sin = Sins[s], Pout = Pouts[s];
    int tiles = (Pout + 14) / 15;
    conv3pool_kernel<<<dim3(tiles * tiles, 16, 16), 256, 0, stream>>>(
        ib, convs_w + (long)(s + 1) * 128 * 128 * 9, ob, Sin, Pout, 0);
    zero_kernel<<<1, 256, 0, stream>>>(stats, 256);
    int P2 = Pout * Pout;
    stats_kernel<<<dim3(128, 16), 256, 0, stream>>>(ob, stats, P2);
    long total = 16L * 128 * P2;
    bnrelu_kernel<<<(int)((total + 255) / 256), 256, 0, stream>>>(
        ob, stats, bn_g + (s + 2) * 128, bn_b + (s + 2) * 128, P2,
        1.f / (16.f * P2), total);
  }

  // ---- tail: LRN -> GEMV -> spectral norm -> sample (overwrites d_out) ----
  lrn_kernel<<<16, 128, 0, stream>>>(bufB);
  gemv_kernel<<<16, 256, 0, stream>>>(bufB, Wr, br, regb);
  sn_kernel<<<1, 1, 0, stream>>>(regb, u0, v0, thetab, mb);
  sample_kernel<<<50176, 256, 0, stream>>>(x, thetab, mb, out);
}